// Round 1
// baseline (814.531 us; speedup 1.0000x reference)
//
#include <hip/hip_runtime.h>
#include <cstdint>
#include <cstddef>

// MultiResHashGrid encode: 1e6 points, 16 levels, 2 feats/level, 2^19 hashmap.
// Output per point: [x,y,z, f(l0,0),f(l0,1), ..., f(l15,0),f(l15,1)] = 35 f32.

#define NPTS     1000000
#define NLEV     16
#define TBL_ENT  524288      // 2^19 entries per level
#define BLK      256
#define OUT_PP   35          // floats per point

// Level params (computed from beta = exp((ln2048-ln16)/15), r_l = floor(16*beta^l)):
// r:  16  22  30  42  58  80  111  153  212  294  406  561  776  1072 1482 2048
// hs: r^3 clamped at 2^19
__device__ constexpr float    kRes[NLEV] = {16.f, 22.f, 30.f, 42.f, 58.f, 80.f, 111.f, 153.f,
                                            212.f, 294.f, 406.f, 561.f, 776.f, 1072.f, 1482.f, 2048.f};
__device__ constexpr uint32_t kHS[NLEV]  = {4096u, 10648u, 27000u, 74088u, 195112u, 512000u,
                                            524288u, 524288u, 524288u, 524288u, 524288u,
                                            524288u, 524288u, 524288u, 524288u, 524288u};

__global__ __launch_bounds__(BLK) void hashgrid_kernel(
    const float* __restrict__ x,
    const float* __restrict__ tables,
    float* __restrict__ out)
{
    __shared__ float smem[BLK * OUT_PP];   // 35840 B

    const int t = threadIdx.x;
    const int i = blockIdx.x * BLK + t;
    const bool active = (i < NPTS);

    float px = 0.f, py = 0.f, pz = 0.f;
    if (active) {
        px = x[3 * i + 0];
        py = x[3 * i + 1];
        pz = x[3 * i + 2];
    }
    smem[t * OUT_PP + 0] = px;
    smem[t * OUT_PP + 1] = py;
    smem[t * OUT_PP + 2] = pz;

    #pragma unroll
    for (int l = 0; l < NLEV; ++l) {
        const float    r  = kRes[l];
        const uint32_t hs = kHS[l];
        const float2* __restrict__ tbl =
            reinterpret_cast<const float2*>(tables) + (size_t)l * TBL_ENT;

        const float xs = px * r, ys = py * r, zs = pz * r;
        const int xi = (int)xs, yi = (int)ys, zi = (int)zs;
        const float xf = xs - (float)xi, yf = ys - (float)yi, zf = zs - (float)zi;

        // hash contributions per dim (prime[0]=1)
        const uint32_t hx0 = (uint32_t)xi;
        const uint32_t hx1 = hx0 + 1u;
        const uint32_t hy0 = (uint32_t)yi * 2654435761u;
        const uint32_t hy1 = hy0 + 2654435761u;
        const uint32_t hz0 = (uint32_t)zi * 805459861u;
        const uint32_t hz1 = hz0 + 805459861u;

        const float wx0 = 1.f - xf, wx1 = xf;
        const float wy0 = 1.f - yf, wy1 = yf;
        const float wz0 = 1.f - zf, wz1 = zf;

        uint32_t hid[8];
        float    w[8];
        #pragma unroll
        for (int c = 0; c < 8; ++c) {
            const uint32_t hxc = (c & 1) ? hx1 : hx0;
            const uint32_t hyc = (c & 2) ? hy1 : hy0;
            const uint32_t hzc = (c & 4) ? hz1 : hz0;
            const uint32_t h = hxc ^ hyc ^ hzc;
            hid[c] = h % hs;   // hs is compile-time: AND for pow2, magic-mul else
            const float wxc = (c & 1) ? wx1 : wx0;
            const float wyc = (c & 2) ? wy1 : wy0;
            const float wzc = (c & 4) ? wz1 : wz0;
            w[c] = wxc * wyc * wzc;
        }

        float2 v[8];
        #pragma unroll
        for (int c = 0; c < 8; ++c) v[c] = tbl[hid[c]];

        float f0 = 0.f, f1 = 0.f;
        #pragma unroll
        for (int c = 0; c < 8; ++c) {
            f0 = fmaf(w[c], v[c].x, f0);
            f1 = fmaf(w[c], v[c].y, f1);
        }

        smem[t * OUT_PP + 3 + 2 * l]     = f0;
        smem[t * OUT_PP + 3 + 2 * l + 1] = f1;
    }

    __syncthreads();

    // Coalesced block write: 256*35 = 8960 floats = 2240 float4 per block.
    const size_t base = (size_t)blockIdx.x * (BLK * OUT_PP);
    const long long remain = (long long)NPTS * OUT_PP - (long long)base;  // >0
    const int n4 = (int)((remain < (long long)(BLK * OUT_PP) ? remain : (long long)(BLK * OUT_PP)) / 4);
    const float4* __restrict__ s4 = reinterpret_cast<const float4*>(smem);
    float4* __restrict__ o4 = reinterpret_cast<float4*>(out + base);
    for (int j = t; j < n4; j += BLK) o4[j] = s4[j];
}

extern "C" void kernel_launch(void* const* d_in, const int* in_sizes, int n_in,
                              void* d_out, int out_size, void* d_ws, size_t ws_size,
                              hipStream_t stream)
{
    const float* x      = (const float*)d_in[0];   // (1e6, 3) f32
    const float* tables = (const float*)d_in[1];   // (16, 2^19, 2) f32
    float* out          = (float*)d_out;           // (1e6, 35) f32

    const int grid = (NPTS + BLK - 1) / BLK;       // 3907
    hashgrid_kernel<<<grid, BLK, 0, stream>>>(x, tables, out);
}

// Round 2
// 539.815 us; speedup vs baseline: 1.5089x; 1.5089x over previous
//
#include <hip/hip_runtime.h>
#include <cstdint>
#include <cstddef>

// MultiResHashGrid encode: 1e6 points, 16 levels, 2 feats/level, 2^19 hashmap.
// Output per point: [x,y,z, f(l0,0),f(l0,1), ..., f(l15,0),f(l15,1)] = 35 f32.
//
// R2 strategy: level-major two-pass.
//   Pass 1: blockIdx = level*CHUNKS + chunk. At any instant the resident block
//           window covers ~half a level -> each XCD L2 holds ~1 active 4MB
//           table instead of all 16 (46MB). Writes float2 features coalesced
//           into level-major workspace ws[l][p].
//   Pass 2: streaming transpose ws -> out rows via LDS, coalesced float4.
// Fallback to the R1 point-major kernel if ws_size < 128 MB.

#define NPTS     1000000
#define NLEV     16
#define TBL_ENT  524288      // 2^19 entries per level
#define BLK      256
#define OUT_PP   35          // floats per point
#define CHUNKS   ((NPTS + BLK - 1) / BLK)   // 3907

// r:  16  22  30  42  58  80  111  153  212  294  406  561  776  1072 1482 2048
// hs: min(r^3, 2^19)
constexpr float    cRes[NLEV] = {16.f, 22.f, 30.f, 42.f, 58.f, 80.f, 111.f, 153.f,
                                 212.f, 294.f, 406.f, 561.f, 776.f, 1072.f, 1482.f, 2048.f};
constexpr uint32_t cHS[NLEV]  = {4096u, 10648u, 27000u, 74088u, 195112u, 512000u,
                                 524288u, 524288u, 524288u, 524288u, 524288u,
                                 524288u, 524288u, 524288u, 524288u, 524288u};

// ---------------- Pass 1: per-level gather, compile-time level params ----------------

template<int L>
__device__ __forceinline__ void do_level(float px, float py, float pz,
                                         const float* __restrict__ tables,
                                         float& f0, float& f1)
{
    constexpr float    r  = cRes[L];
    constexpr uint32_t hs = cHS[L];
    const float2* __restrict__ tbl =
        reinterpret_cast<const float2*>(tables) + (size_t)L * TBL_ENT;

    const float xs = px * r, ys = py * r, zs = pz * r;
    const int xi = (int)xs, yi = (int)ys, zi = (int)zs;
    const float xf = xs - (float)xi, yf = ys - (float)yi, zf = zs - (float)zi;

    const uint32_t hx0 = (uint32_t)xi;
    const uint32_t hx1 = hx0 + 1u;
    const uint32_t hy0 = (uint32_t)yi * 2654435761u;
    const uint32_t hy1 = hy0 + 2654435761u;
    const uint32_t hz0 = (uint32_t)zi * 805459861u;
    const uint32_t hz1 = hz0 + 805459861u;

    const float wx0 = 1.f - xf, wx1 = xf;
    const float wy0 = 1.f - yf, wy1 = yf;
    const float wz0 = 1.f - zf, wz1 = zf;

    uint32_t hid[8];
    float    w[8];
    #pragma unroll
    for (int c = 0; c < 8; ++c) {
        const uint32_t hxc = (c & 1) ? hx1 : hx0;
        const uint32_t hyc = (c & 2) ? hy1 : hy0;
        const uint32_t hzc = (c & 4) ? hz1 : hz0;
        hid[c] = (hxc ^ hyc ^ hzc) % hs;   // hs compile-time: AND or magic-mul
        const float wxc = (c & 1) ? wx1 : wx0;
        const float wyc = (c & 2) ? wy1 : wy0;
        const float wzc = (c & 4) ? wz1 : wz0;
        w[c] = wxc * wyc * wzc;
    }

    float2 v[8];
    #pragma unroll
    for (int c = 0; c < 8; ++c) v[c] = tbl[hid[c]];

    f0 = 0.f; f1 = 0.f;
    #pragma unroll
    for (int c = 0; c < 8; ++c) {
        f0 = fmaf(w[c], v[c].x, f0);
        f1 = fmaf(w[c], v[c].y, f1);
    }
}

__global__ __launch_bounds__(BLK) void hashgrid_pass1(
    const float* __restrict__ x,
    const float* __restrict__ tables,
    float2* __restrict__ ws)
{
    const int b = blockIdx.x;
    const int l = b / CHUNKS;          // level (block-uniform)
    const int c = b - l * CHUNKS;      // point chunk
    const int i = c * BLK + threadIdx.x;
    if (i >= NPTS) return;

    const float px = x[3 * i + 0];
    const float py = x[3 * i + 1];
    const float pz = x[3 * i + 2];

    float f0, f1;
    switch (l) {
        case 0:  do_level<0 >(px, py, pz, tables, f0, f1); break;
        case 1:  do_level<1 >(px, py, pz, tables, f0, f1); break;
        case 2:  do_level<2 >(px, py, pz, tables, f0, f1); break;
        case 3:  do_level<3 >(px, py, pz, tables, f0, f1); break;
        case 4:  do_level<4 >(px, py, pz, tables, f0, f1); break;
        case 5:  do_level<5 >(px, py, pz, tables, f0, f1); break;
        case 6:  do_level<6 >(px, py, pz, tables, f0, f1); break;
        case 7:  do_level<7 >(px, py, pz, tables, f0, f1); break;
        case 8:  do_level<8 >(px, py, pz, tables, f0, f1); break;
        case 9:  do_level<9 >(px, py, pz, tables, f0, f1); break;
        case 10: do_level<10>(px, py, pz, tables, f0, f1); break;
        case 11: do_level<11>(px, py, pz, tables, f0, f1); break;
        case 12: do_level<12>(px, py, pz, tables, f0, f1); break;
        case 13: do_level<13>(px, py, pz, tables, f0, f1); break;
        case 14: do_level<14>(px, py, pz, tables, f0, f1); break;
        default: do_level<15>(px, py, pz, tables, f0, f1); break;
    }

    ws[(size_t)l * NPTS + i] = make_float2(f0, f1);   // coalesced 8B
}

// ---------------- Pass 2: transpose ws (level-major) -> out (point-major) ----------------

__global__ __launch_bounds__(BLK) void hashgrid_pass2(
    const float* __restrict__ x,
    const float2* __restrict__ ws,
    float* __restrict__ out)
{
    __shared__ float smem[BLK * OUT_PP];   // 35840 B

    const int t = threadIdx.x;
    const int base = blockIdx.x * BLK;
    const int i = base + t;
    const bool active = (i < NPTS);

    if (active) {
        smem[t * OUT_PP + 0] = x[3 * i + 0];
        smem[t * OUT_PP + 1] = x[3 * i + 1];
        smem[t * OUT_PP + 2] = x[3 * i + 2];
        #pragma unroll
        for (int l = 0; l < NLEV; ++l) {
            const float2 v = ws[(size_t)l * NPTS + i];   // coalesced 8B
            smem[t * OUT_PP + 3 + 2 * l]     = v.x;
            smem[t * OUT_PP + 3 + 2 * l + 1] = v.y;
        }
    }
    __syncthreads();

    const size_t gbase = (size_t)blockIdx.x * (BLK * OUT_PP);
    const long long remain = (long long)NPTS * OUT_PP - (long long)gbase;
    const int n4 = (int)((remain < (long long)(BLK * OUT_PP) ? remain : (long long)(BLK * OUT_PP)) / 4);
    const float4* __restrict__ s4 = reinterpret_cast<const float4*>(smem);
    float4* __restrict__ o4 = reinterpret_cast<float4*>(out + gbase);
    for (int j = t; j < n4; j += BLK) o4[j] = s4[j];
}

// ---------------- Fallback (R1 point-major single kernel) ----------------

__global__ __launch_bounds__(BLK) void hashgrid_fused(
    const float* __restrict__ x,
    const float* __restrict__ tables,
    float* __restrict__ out)
{
    __shared__ float smem[BLK * OUT_PP];

    const int t = threadIdx.x;
    const int i = blockIdx.x * BLK + t;
    const bool active = (i < NPTS);

    float px = 0.f, py = 0.f, pz = 0.f;
    if (active) {
        px = x[3 * i + 0];
        py = x[3 * i + 1];
        pz = x[3 * i + 2];
    }
    smem[t * OUT_PP + 0] = px;
    smem[t * OUT_PP + 1] = py;
    smem[t * OUT_PP + 2] = pz;

    float f0, f1;
    #pragma unroll
    for (int l = 0; l < NLEV; ++l) {
        switch (l) {
            case 0:  do_level<0 >(px, py, pz, tables, f0, f1); break;
            case 1:  do_level<1 >(px, py, pz, tables, f0, f1); break;
            case 2:  do_level<2 >(px, py, pz, tables, f0, f1); break;
            case 3:  do_level<3 >(px, py, pz, tables, f0, f1); break;
            case 4:  do_level<4 >(px, py, pz, tables, f0, f1); break;
            case 5:  do_level<5 >(px, py, pz, tables, f0, f1); break;
            case 6:  do_level<6 >(px, py, pz, tables, f0, f1); break;
            case 7:  do_level<7 >(px, py, pz, tables, f0, f1); break;
            case 8:  do_level<8 >(px, py, pz, tables, f0, f1); break;
            case 9:  do_level<9 >(px, py, pz, tables, f0, f1); break;
            case 10: do_level<10>(px, py, pz, tables, f0, f1); break;
            case 11: do_level<11>(px, py, pz, tables, f0, f1); break;
            case 12: do_level<12>(px, py, pz, tables, f0, f1); break;
            case 13: do_level<13>(px, py, pz, tables, f0, f1); break;
            default: do_level<15>(px, py, pz, tables, f0, f1); break;
        }
        smem[t * OUT_PP + 3 + 2 * l]     = f0;
        smem[t * OUT_PP + 3 + 2 * l + 1] = f1;
    }

    __syncthreads();

    const size_t gbase = (size_t)blockIdx.x * (BLK * OUT_PP);
    const long long remain = (long long)NPTS * OUT_PP - (long long)gbase;
    const int n4 = (int)((remain < (long long)(BLK * OUT_PP) ? remain : (long long)(BLK * OUT_PP)) / 4);
    const float4* __restrict__ s4 = reinterpret_cast<const float4*>(smem);
    float4* __restrict__ o4 = reinterpret_cast<float4*>(out + gbase);
    for (int j = t; j < n4; j += BLK) o4[j] = s4[j];
}

extern "C" void kernel_launch(void* const* d_in, const int* in_sizes, int n_in,
                              void* d_out, int out_size, void* d_ws, size_t ws_size,
                              hipStream_t stream)
{
    const float* x      = (const float*)d_in[0];   // (1e6, 3) f32
    const float* tables = (const float*)d_in[1];   // (16, 2^19, 2) f32
    float* out          = (float*)d_out;           // (1e6, 35) f32

    const size_t ws_needed = (size_t)NLEV * NPTS * sizeof(float2);   // 128 MB

    if (ws_size >= ws_needed) {
        float2* ws = (float2*)d_ws;
        hashgrid_pass1<<<NLEV * CHUNKS, BLK, 0, stream>>>(x, tables, ws);
        hashgrid_pass2<<<CHUNKS, BLK, 0, stream>>>(x, ws, out);
    } else {
        hashgrid_fused<<<CHUNKS, BLK, 0, stream>>>(x, tables, out);
    }
}